// Round 6
// baseline (465.622 us; speedup 1.0000x reference)
//
#include <hip/hip_runtime.h>

// ---------------------------------------------------------------------------
// Attention block: out = SDPA(RoPE(x@wq^T), RoPE(x@wk^T), x@wv^T) @ wo^T
// B=2 S=2048 D=2048 H=16 HD=128, causal, start_pos=0.
// R6: flash -> 64-row Q tiles, each block runs tiles (31-p, p) SEQUENTIALLY
//     (uniform 33 iters/block, no dispatch-order assumptions, no tail);
//     K LDS-dbuf with cross-job parity, V register-reload, swizzled P.
//     gemm_out reverted to BK=32 (known 56us); gemm_qkv stays BK=64.
// ---------------------------------------------------------------------------

typedef __bf16 bf16_t;
typedef __bf16 bf16x4 __attribute__((ext_vector_type(4)));
typedef __bf16 bf16x8 __attribute__((ext_vector_type(8)));
typedef float  f32x4  __attribute__((ext_vector_type(4)));

#define DEV __device__ __forceinline__

DEV void async_copy16(const bf16_t* g, bf16_t* lds_uniform_base) {
    __builtin_amdgcn_global_load_lds(
        (const __attribute__((address_space(1))) void*)g,
        (__attribute__((address_space(3))) void*)lds_uniform_base,
        16, 0, 0);
}

// ---------------------------------------------------------------------------
__global__ void cast_all(const float* __restrict__ x,  const float* __restrict__ wq,
                         const float* __restrict__ wk, const float* __restrict__ wv,
                         const float* __restrict__ wo,
                         bf16_t* __restrict__ xb, bf16_t* __restrict__ W3,
                         bf16_t* __restrict__ wob)
{
    const int i = blockIdx.x * blockDim.x + threadIdx.x;
    const float4* src;
    bf16x4* dst;
    if (i < 2097152) {
        src = (const float4*)x + i;
        dst = (bf16x4*)xb + i;
    } else {
        const int j   = i - 2097152;
        const int r   = j >> 20;
        const int off = j & 1048575;
        const float* s4 = (r == 0) ? wq : (r == 1) ? wk : (r == 2) ? wv : wo;
        src = (const float4*)s4 + off;
        dst = (r < 3) ? ((bf16x4*)W3 + (long)r * 1048576 + off)
                      : ((bf16x4*)wob + off);
    }
    const float4 v = *src;
    bf16x4 o = { (bf16_t)v.x, (bf16_t)v.y, (bf16_t)v.z, (bf16_t)v.w };
    *dst = o;
}

// ---------------------------------------------------------------------------
// Fused QKV projection: C = x(4096x2048) * W3(6144x2048)^T. BK=64, XOR
// chunk swizzle (conflict-free ds_read_b128). R5 version (improved vs BK=32).
// n in [0,2048): RoPE -> Q ; [2048,4096): RoPE -> K ; [4096,6144): V^T.
// V^T layout: VT[((b*16+h)*128 + d)*2048 + s]
// ---------------------------------------------------------------------------
__global__ __launch_bounds__(256)
void gemm_qkv(const bf16_t* __restrict__ A, const bf16_t* __restrict__ Bm,
              bf16_t* __restrict__ Qo, bf16_t* __restrict__ Ko,
              bf16_t* __restrict__ VTo,
              const float* __restrict__ cosT, const float* __restrict__ sinT)
{
    constexpr int K = 2048;
    __shared__ bf16_t As[128 * 64];
    __shared__ bf16_t Bs[128 * 64];

    const int tid  = threadIdx.x;
    const int w    = tid >> 6;
    const int lane = tid & 63;
    const int l16  = lane & 15;
    const int quad = lane >> 4;
    const int l7   = l16 & 7;
    const int wm   = w >> 1, wn = w & 1;

    const int id   = blockIdx.x;
    const int xcd  = id & 7;
    const int slot = id >> 3;           // 0..191
    const int nl   = slot % 6;
    const int ml   = slot / 6;
    const long n0  = (long)(xcd * 6 + nl) * 128;
    const long m0  = (long)ml * 128;

    f32x4 acc[4][4] = {};

    const bf16_t* Ag[4];
    const bf16_t* Bg[4];
    #pragma unroll
    for (int i = 0; i < 4; ++i) {
        const int c   = i * 256 + tid;
        const int row = c >> 3;
        const int col = ((c & 7) ^ (row & 7)) * 8;
        Ag[i] = A  + (m0 + row) * K + col;
        Bg[i] = Bm + (n0 + row) * K + col;
    }

    for (int k0 = 0; k0 < K; k0 += 64) {
        __syncthreads();
        #pragma unroll
        for (int i = 0; i < 4; ++i) {
            async_copy16(Ag[i] + k0, As + i * 2048 + w * 512);
            async_copy16(Bg[i] + k0, Bs + i * 2048 + w * 512);
        }
        __syncthreads();

        #pragma unroll
        for (int kc = 0; kc < 2; ++kc) {
            bf16x8 af[4], bfr[4];
            #pragma unroll
            for (int t = 0; t < 4; ++t) {
                const int cs = ((kc * 4 + quad) ^ l7) * 8;
                af[t]  = *(const bf16x8*)&As[(wm * 64 + t * 16 + l16) * 64 + cs];
                bfr[t] = *(const bf16x8*)&Bs[(wn * 64 + t * 16 + l16) * 64 + cs];
            }
            #pragma unroll
            for (int mt = 0; mt < 4; ++mt)
                #pragma unroll
                for (int nt = 0; nt < 4; ++nt)
                    acc[mt][nt] = __builtin_amdgcn_mfma_f32_16x16x32_bf16(
                        af[mt], bfr[nt], acc[mt][nt], 0, 0, 0);
        }
    }

    const int region = (int)(n0 >> 11);   // block-uniform: 0=Q, 1=K, 2=V
    #pragma unroll
    for (int mt = 0; mt < 4; ++mt) {
        #pragma unroll
        for (int nt = 0; nt < 4; ++nt) {
            if (region < 2) {
                bf16_t* dst = (region == 0) ? Qo : Ko;
                #pragma unroll
                for (int r = 0; r < 4; ++r) {
                    const long m = m0 + wm * 64 + mt * 16 + quad * 4 + r;
                    const long n = n0 + wn * 64 + nt * 16 + l16;
                    float v = acc[mt][nt][r];
                    const float partner = __shfl_xor(v, 1);
                    const int d    = (int)n & 127;
                    const int fidx = ((int)m & 2047) * 64 + (d >> 1);
                    const float c = cosT[fidx], s = sinT[fidx];
                    v = ((int)n & 1) ? fmaf(partner, s, v * c)
                                     : (v * c - partner * s);
                    dst[m * 2048 + (n & 2047)] = (bf16_t)v;
                }
            } else {
                const long m  = m0 + wm * 64 + mt * 16 + quad * 4;   // r=0 base
                const int  np = (int)(n0 + wn * 64 + nt * 16 + l16) - 4096;
                bf16x4 pk;
                #pragma unroll
                for (int r = 0; r < 4; ++r) pk[r] = (bf16_t)acc[mt][nt][r];
                const int b  = (int)(m >> 11);
                const int s0 = (int)m & 2047;
                const long idx = ((long)(b * 16 + (np >> 7)) * 128 + (np & 127)) * 2048 + s0;
                *(bf16x4*)&VTo[idx] = pk;
            }
        }
    }
}

// ---------------------------------------------------------------------------
// Output projection: C = Ob(4096x2048) * wo(2048x2048)^T -> fp32. BK=32
// (R4 version, known-good 56us).
// ---------------------------------------------------------------------------
__global__ __launch_bounds__(256)
void gemm_out(const bf16_t* __restrict__ A, const bf16_t* __restrict__ Bm,
              float* __restrict__ Cp)
{
    constexpr int K = 2048, N = 2048;
    __shared__ bf16_t As[128 * 32];
    __shared__ bf16_t Bs[128 * 32];

    const int tid  = threadIdx.x;
    const int w    = tid >> 6;
    const int lane = tid & 63;
    const int l16  = lane & 15;
    const int quad = lane >> 4;
    const int wm   = w >> 1, wn = w & 1;

    const int id   = blockIdx.x;
    const int xcd  = id & 7;
    const int slot = id >> 3;           // 0..63
    const long n0  = (long)(xcd * 2 + (slot & 1)) * 128;
    const long m0  = (long)(slot >> 1) * 128;

    f32x4 acc[4][4] = {};

    const int srow = tid >> 2;
    const int soff = (tid & 3) * 8;
    const bf16_t* Ag = A  + (m0 + srow) * K + soff;
    const bf16_t* Bg = Bm + (n0 + srow) * K + soff;

    for (int k0 = 0; k0 < K; k0 += 32) {
        __syncthreads();
        async_copy16(Ag + k0,          As + w * 512);
        async_copy16(Ag + 64 * K + k0, As + 2048 + w * 512);
        async_copy16(Bg + k0,          Bs + w * 512);
        async_copy16(Bg + 64 * K + k0, Bs + 2048 + w * 512);
        __syncthreads();

        bf16x8 af[4], bfr[4];
        #pragma unroll
        for (int t = 0; t < 4; ++t) {
            af[t]  = *(const bf16x8*)&As[(wm * 64 + t * 16 + l16) * 32 + quad * 8];
            bfr[t] = *(const bf16x8*)&Bs[(wn * 64 + t * 16 + l16) * 32 + quad * 8];
        }
        #pragma unroll
        for (int mt = 0; mt < 4; ++mt)
            #pragma unroll
            for (int nt = 0; nt < 4; ++nt)
                acc[mt][nt] = __builtin_amdgcn_mfma_f32_16x16x32_bf16(
                    af[mt], bfr[nt], acc[mt][nt], 0, 0, 0);
    }

    #pragma unroll
    for (int mt = 0; mt < 4; ++mt)
        #pragma unroll
        for (int nt = 0; nt < 4; ++nt)
            #pragma unroll
            for (int r = 0; r < 4; ++r) {
                const long m = m0 + wm * 64 + mt * 16 + quad * 4 + r;
                const long n = n0 + wn * 64 + nt * 16 + l16;
                Cp[m * N + n] = acc[mt][nt][r];
            }
}

// ---------------------------------------------------------------------------
// Flash attention R6. Grid 512 x 256thr (4 waves). Block (p, bh) processes
// q-tiles qtA=31-p then qtB=p (64 rows each) SEQUENTIALLY: every block runs
// exactly 33 k-iters -> no causal tail, no dispatch-order assumptions.
// Wave w owns q-rows [w*16, w*16+16); all waves active every iter (diag
// masking only on kt==qt). K: LDS double-buffer, global parity counter g
// carries across the job boundary (job0's last iter prefetches job1's K[0]).
// V^T: 16 bf16x8 register slots reloaded right after last use (wave-
// identical addresses -> L1 broadcast). P: XOR-swizzled [64][64] LDS
// (conflict-free b64 writes / b128 reads), wave-private rows, no barrier.
// Fixed-M softmax: p = exp2(z*SC - 24). LDS 40KB.
// ---------------------------------------------------------------------------
__global__ __launch_bounds__(256, 2)
void flash_attn(const bf16_t* __restrict__ Q, const bf16_t* __restrict__ Kg,
                const bf16_t* __restrict__ VT, bf16_t* __restrict__ O)
{
    constexpr int S = 2048, D = 2048;
    __shared__ bf16_t Kb[2][64 * 128];   // [k_row][d], chunk-swizzled
    __shared__ bf16_t Ps[64 * 64];       // [q_row][k], chunk-swizzled

    const int tid  = threadIdx.x;
    const int w    = tid >> 6, lane = tid & 63, l16 = lane & 15, quad = lane >> 4;
    const int l7   = l16 & 7;

    const int id   = blockIdx.x;
    const int bh   = id & 31;
    const int p    = id >> 5;            // 0..15
    const int b    = bh >> 4, h = bh & 15;

    // K staging offsets (XOR chunk swizzle over 16 chunks/row)
    int koff[4];
    #pragma unroll
    for (int i = 0; i < 4; ++i) {
        const int c  = i * 256 + tid;
        const int kr = c >> 4, cs = c & 15;
        const int cc = (cs & 8) | ((cs & 7) ^ (kr & 7));
        koff[i] = kr * D + cc * 8;
    }
    const bf16_t* Kst = Kg + (long)b * S * D + h * 128;
    const bf16_t* Vl  = VT + (long)bh * 128 * S + (long)l16 * S + quad * 8;

    const float SC = 0.08838834764831845f * 1.44269504088896340f;

    // prologue: stage K[0] -> Kb[0], V[0] -> registers
    #pragma unroll
    for (int i = 0; i < 4; ++i)
        async_copy16(Kst + koff[i], &Kb[0][i * 2048 + w * 512]);
    bf16x8 vf[2][8];
    #pragma unroll
    for (int ks = 0; ks < 2; ++ks)
        #pragma unroll
        for (int nv = 0; nv < 8; ++nv)
            vf[ks][nv] = *(const bf16x8*)(Vl + (long)nv * 16 * S + ks * 32);

    int g = 0;   // global iteration counter -> K buffer parity
    for (int job = 0; job < 2; ++job) {
        const int qt = job ? p : (31 - p);
        const int q0 = qt * 64;

        // Q fragments for this tile (B-operand: n = q-row l16, k = d)
        bf16x8 qf[4];
        {
            const bf16_t* qp = Q + (long)(b * S + q0 + w * 16 + l16) * D
                                 + h * 128 + quad * 8;
            #pragma unroll
            for (int kk = 0; kk < 4; ++kk)
                qf[kk] = *(const bf16x8*)(qp + kk * 32);
        }

        f32x4 oacc[8] = {};
        float li = 0.f;

        for (int kt = 0; kt <= qt; ++kt, ++g) {
            __syncthreads();   // Kb[g&1]+vf landed; Kb[(g+1)&1] reads done
            // next k-tile: within tile, or job1's K[0] at the job0 boundary
            const int nk = (kt < qt) ? kt + 1 : (job == 0 ? 0 : kt);
            #pragma unroll
            for (int i = 0; i < 4; ++i)
                async_copy16(Kst + (long)nk * 64 * D + koff[i],
                             &Kb[(g + 1) & 1][i * 2048 + w * 512]);

            // ---- S^T = K·Q^T : rows = 64 k, cols = 16 q (this wave) ----
            f32x4 sc[4] = {};
            const bf16_t* Kcur = Kb[g & 1];
            #pragma unroll
            for (int kk = 0; kk < 4; ++kk)
                #pragma unroll
                for (int mt = 0; mt < 4; ++mt) {
                    const int cc = kk * 4 + quad;
                    const bf16x8 kf = *(const bf16x8*)
                        &Kcur[(mt * 16 + l16) * 128 + ((cc & 8) | ((cc & 7) ^ l7)) * 8];
                    sc[mt] = __builtin_amdgcn_mfma_f32_16x16x32_bf16(
                        kf, qf[kk], sc[mt], 0, 0, 0);
                }

            // ---- fixed-M softmax + swizzled packed P writes ----
            const bool diag = (kt == qt);
            const int qloc  = w * 16 + l16;     // but mask uses within-tile q
            float rs = 0.f;
            #pragma unroll
            for (int mt = 0; mt < 4; ++mt) {
                bf16x4 pk;
                #pragma unroll
                for (int r = 0; r < 4; ++r) {
                    const int kloc = mt * 16 + quad * 4 + r;
                    const float pv = (diag && kloc > qloc) ? 0.f
                                   : exp2f(sc[mt][r] * SC - 24.0f);
                    rs += pv;
                    pk[r] = (bf16_t)pv;
                }
                const int slot = (mt * 2 + (quad >> 1)) ^ l7;
                *(bf16x4*)&Ps[(w * 16 + l16) * 64 + slot * 8 + (quad & 1) * 4] = pk;
            }
            li += rs;

            // ---- O += P·V^T ; reload each vf slot right after last use ----
            #pragma unroll
            for (int ks = 0; ks < 2; ++ks) {
                const bf16x8 pf = *(const bf16x8*)
                    &Ps[(w * 16 + l16) * 64 + ((ks * 4 + quad) ^ l7) * 8];
                #pragma unroll
                for (int nv = 0; nv < 8; ++nv) {
                    const bf16x8 vcur = vf[ks][nv];
                    vf[ks][nv] = *(const bf16x8*)
                        (Vl + (long)nv * 16 * S + ks * 32 + (long)nk * 64);
                    oacc[nv] = __builtin_amdgcn_mfma_f32_16x16x32_bf16(
                        pf, vcur, oacc[nv], 0, 0, 0);
                }
            }
        }

        // ---- epilogue for this tile ----
        li += __shfl_xor(li, 16);
        li += __shfl_xor(li, 32);
        const float inv = 1.0f / li;
        #pragma unroll
        for (int r = 0; r < 4; ++r) {
            const float invr = __shfl(inv, quad * 4 + r);
            const long  row  = (long)(b * S + q0 + w * 16 + quad * 4 + r);
            #pragma unroll
            for (int nv = 0; nv < 8; ++nv)
                O[row * D + h * 128 + nv * 16 + l16] = (bf16_t)(oacc[nv][r] * invr);
        }
    }
}

// ---------------------------------------------------------------------------
extern "C" void kernel_launch(void* const* d_in, const int* in_sizes, int n_in,
                              void* d_out, int out_size, void* d_ws, size_t ws_size,
                              hipStream_t stream) {
    const float* x  = (const float*)d_in[0];
    const float* wq = (const float*)d_in[1];
    const float* wk = (const float*)d_in[2];
    const float* wv = (const float*)d_in[3];
    const float* wo = (const float*)d_in[4];
    const float* fc = (const float*)d_in[5];
    const float* fs = (const float*)d_in[6];

    char* ws = (char*)d_ws;
    bf16_t* xb  = (bf16_t*)(ws + 0);
    bf16_t* W3  = (bf16_t*)(ws + (16l << 20));
    bf16_t* wob = (bf16_t*)(ws + (40l << 20));
    bf16_t* Qb  = (bf16_t*)(ws + (48l << 20));
    bf16_t* Kb  = (bf16_t*)(ws + (64l << 20));
    bf16_t* VTb = (bf16_t*)(ws + (80l << 20));
    bf16_t* Ob  = xb;   // x dead after QKV projection

    cast_all<<<24576, 256, 0, stream>>>(x, wq, wk, wv, wo, xb, W3, wob);

    gemm_qkv<<<1536, 256, 0, stream>>>(xb, W3, Qb, Kb, VTb, fc, fs);

    flash_attn<<<512, 256, 0, stream>>>(Qb, Kb, VTb, Ob);

    gemm_out<<<512, 256, 0, stream>>>(Ob, wob, (float*)d_out);
}

// Round 7
// 399.280 us; speedup vs baseline: 1.1662x; 1.1662x over previous
//
#include <hip/hip_runtime.h>

// ---------------------------------------------------------------------------
// Attention block: out = SDPA(RoPE(x@wq^T), RoPE(x@wk^T), x@wv^T) @ wo^T
// B=2 S=2048 D=2048 H=16 HD=128, causal, start_pos=0.
// R7: flash = R5 shape (128-row Q tiles, grid 512) but ALL global traffic
//     (K and V, both LDS double-buffered) issued as async copies at the TOP
//     of each iteration -> the per-iter barrier's vmcnt(0) drain waits on
//     loads issued a full iteration earlier (~0 exposed latency). No global
//     ->VGPR loads inside the k-loop. One barrier per iter.
// ---------------------------------------------------------------------------

typedef __bf16 bf16_t;
typedef __bf16 bf16x4 __attribute__((ext_vector_type(4)));
typedef __bf16 bf16x8 __attribute__((ext_vector_type(8)));
typedef float  f32x4  __attribute__((ext_vector_type(4)));

#define DEV __device__ __forceinline__

DEV void async_copy16(const bf16_t* g, bf16_t* lds_uniform_base) {
    __builtin_amdgcn_global_load_lds(
        (const __attribute__((address_space(1))) void*)g,
        (__attribute__((address_space(3))) void*)lds_uniform_base,
        16, 0, 0);
}

// ---------------------------------------------------------------------------
__global__ void cast_all(const float* __restrict__ x,  const float* __restrict__ wq,
                         const float* __restrict__ wk, const float* __restrict__ wv,
                         const float* __restrict__ wo,
                         bf16_t* __restrict__ xb, bf16_t* __restrict__ W3,
                         bf16_t* __restrict__ wob)
{
    const int i = blockIdx.x * blockDim.x + threadIdx.x;
    const float4* src;
    bf16x4* dst;
    if (i < 2097152) {
        src = (const float4*)x + i;
        dst = (bf16x4*)xb + i;
    } else {
        const int j   = i - 2097152;
        const int r   = j >> 20;
        const int off = j & 1048575;
        const float* s4 = (r == 0) ? wq : (r == 1) ? wk : (r == 2) ? wv : wo;
        src = (const float4*)s4 + off;
        dst = (r < 3) ? ((bf16x4*)W3 + (long)r * 1048576 + off)
                      : ((bf16x4*)wob + off);
    }
    const float4 v = *src;
    bf16x4 o = { (bf16_t)v.x, (bf16_t)v.y, (bf16_t)v.z, (bf16_t)v.w };
    *dst = o;
}

// ---------------------------------------------------------------------------
// Fused QKV projection: C = x(4096x2048) * W3(6144x2048)^T. BK=64, XOR
// chunk swizzle (conflict-free ds_read_b128). Unchanged from R5/R6.
// n in [0,2048): RoPE -> Q ; [2048,4096): RoPE -> K ; [4096,6144): V^T.
// V^T layout: VT[((b*16+h)*128 + d)*2048 + s]
// ---------------------------------------------------------------------------
__global__ __launch_bounds__(256)
void gemm_qkv(const bf16_t* __restrict__ A, const bf16_t* __restrict__ Bm,
              bf16_t* __restrict__ Qo, bf16_t* __restrict__ Ko,
              bf16_t* __restrict__ VTo,
              const float* __restrict__ cosT, const float* __restrict__ sinT)
{
    constexpr int K = 2048;
    __shared__ bf16_t As[128 * 64];
    __shared__ bf16_t Bs[128 * 64];

    const int tid  = threadIdx.x;
    const int w    = tid >> 6;
    const int lane = tid & 63;
    const int l16  = lane & 15;
    const int quad = lane >> 4;
    const int l7   = l16 & 7;
    const int wm   = w >> 1, wn = w & 1;

    const int id   = blockIdx.x;
    const int xcd  = id & 7;
    const int slot = id >> 3;           // 0..191
    const int nl   = slot % 6;
    const int ml   = slot / 6;
    const long n0  = (long)(xcd * 6 + nl) * 128;
    const long m0  = (long)ml * 128;

    f32x4 acc[4][4] = {};

    const bf16_t* Ag[4];
    const bf16_t* Bg[4];
    #pragma unroll
    for (int i = 0; i < 4; ++i) {
        const int c   = i * 256 + tid;
        const int row = c >> 3;
        const int col = ((c & 7) ^ (row & 7)) * 8;
        Ag[i] = A  + (m0 + row) * K + col;
        Bg[i] = Bm + (n0 + row) * K + col;
    }

    for (int k0 = 0; k0 < K; k0 += 64) {
        __syncthreads();
        #pragma unroll
        for (int i = 0; i < 4; ++i) {
            async_copy16(Ag[i] + k0, As + i * 2048 + w * 512);
            async_copy16(Bg[i] + k0, Bs + i * 2048 + w * 512);
        }
        __syncthreads();

        #pragma unroll
        for (int kc = 0; kc < 2; ++kc) {
            bf16x8 af[4], bfr[4];
            #pragma unroll
            for (int t = 0; t < 4; ++t) {
                const int cs = ((kc * 4 + quad) ^ l7) * 8;
                af[t]  = *(const bf16x8*)&As[(wm * 64 + t * 16 + l16) * 64 + cs];
                bfr[t] = *(const bf16x8*)&Bs[(wn * 64 + t * 16 + l16) * 64 + cs];
            }
            #pragma unroll
            for (int mt = 0; mt < 4; ++mt)
                #pragma unroll
                for (int nt = 0; nt < 4; ++nt)
                    acc[mt][nt] = __builtin_amdgcn_mfma_f32_16x16x32_bf16(
                        af[mt], bfr[nt], acc[mt][nt], 0, 0, 0);
        }
    }

    const int region = (int)(n0 >> 11);   // block-uniform: 0=Q, 1=K, 2=V
    #pragma unroll
    for (int mt = 0; mt < 4; ++mt) {
        #pragma unroll
        for (int nt = 0; nt < 4; ++nt) {
            if (region < 2) {
                bf16_t* dst = (region == 0) ? Qo : Ko;
                #pragma unroll
                for (int r = 0; r < 4; ++r) {
                    const long m = m0 + wm * 64 + mt * 16 + quad * 4 + r;
                    const long n = n0 + wn * 64 + nt * 16 + l16;
                    float v = acc[mt][nt][r];
                    const float partner = __shfl_xor(v, 1);
                    const int d    = (int)n & 127;
                    const int fidx = ((int)m & 2047) * 64 + (d >> 1);
                    const float c = cosT[fidx], s = sinT[fidx];
                    v = ((int)n & 1) ? fmaf(partner, s, v * c)
                                     : (v * c - partner * s);
                    dst[m * 2048 + (n & 2047)] = (bf16_t)v;
                }
            } else {
                const long m  = m0 + wm * 64 + mt * 16 + quad * 4;   // r=0 base
                const int  np = (int)(n0 + wn * 64 + nt * 16 + l16) - 4096;
                bf16x4 pk;
                #pragma unroll
                for (int r = 0; r < 4; ++r) pk[r] = (bf16_t)acc[mt][nt][r];
                const int b  = (int)(m >> 11);
                const int s0 = (int)m & 2047;
                const long idx = ((long)(b * 16 + (np >> 7)) * 128 + (np & 127)) * 2048 + s0;
                *(bf16x4*)&VTo[idx] = pk;
            }
        }
    }
}

// ---------------------------------------------------------------------------
// Output projection: C = Ob(4096x2048) * wo(2048x2048)^T -> fp32. BK=32.
// ---------------------------------------------------------------------------
__global__ __launch_bounds__(256)
void gemm_out(const bf16_t* __restrict__ A, const bf16_t* __restrict__ Bm,
              float* __restrict__ Cp)
{
    constexpr int K = 2048, N = 2048;
    __shared__ bf16_t As[128 * 32];
    __shared__ bf16_t Bs[128 * 32];

    const int tid  = threadIdx.x;
    const int w    = tid >> 6;
    const int lane = tid & 63;
    const int l16  = lane & 15;
    const int quad = lane >> 4;
    const int wm   = w >> 1, wn = w & 1;

    const int id   = blockIdx.x;
    const int xcd  = id & 7;
    const int slot = id >> 3;           // 0..63
    const long n0  = (long)(xcd * 2 + (slot & 1)) * 128;
    const long m0  = (long)(slot >> 1) * 128;

    f32x4 acc[4][4] = {};

    const int srow = tid >> 2;
    const int soff = (tid & 3) * 8;
    const bf16_t* Ag = A  + (m0 + srow) * K + soff;
    const bf16_t* Bg = Bm + (n0 + srow) * K + soff;

    for (int k0 = 0; k0 < K; k0 += 32) {
        __syncthreads();
        async_copy16(Ag + k0,          As + w * 512);
        async_copy16(Ag + 64 * K + k0, As + 2048 + w * 512);
        async_copy16(Bg + k0,          Bs + w * 512);
        async_copy16(Bg + 64 * K + k0, Bs + 2048 + w * 512);
        __syncthreads();

        bf16x8 af[4], bfr[4];
        #pragma unroll
        for (int t = 0; t < 4; ++t) {
            af[t]  = *(const bf16x8*)&As[(wm * 64 + t * 16 + l16) * 32 + quad * 8];
            bfr[t] = *(const bf16x8*)&Bs[(wn * 64 + t * 16 + l16) * 32 + quad * 8];
        }
        #pragma unroll
        for (int mt = 0; mt < 4; ++mt)
            #pragma unroll
            for (int nt = 0; nt < 4; ++nt)
                acc[mt][nt] = __builtin_amdgcn_mfma_f32_16x16x32_bf16(
                    af[mt], bfr[nt], acc[mt][nt], 0, 0, 0);
    }

    #pragma unroll
    for (int mt = 0; mt < 4; ++mt)
        #pragma unroll
        for (int nt = 0; nt < 4; ++nt)
            #pragma unroll
            for (int r = 0; r < 4; ++r) {
                const long m = m0 + wm * 64 + mt * 16 + quad * 4 + r;
                const long n = n0 + wn * 64 + nt * 16 + l16;
                Cp[m * N + n] = acc[mt][nt][r];
            }
}

// ---------------------------------------------------------------------------
// Flash attention R7. Grid 512, 4 waves; 128-row Q tile, wave owns 32 rows.
// K [2][64x128] and V^T [2][128x64] both LDS double-buffered, chunk-swizzled,
// staged ONLY at the top of each iteration (8 async_copy16/thread) for iter
// kt+1 -> the single per-iter barrier drains loads issued one full iteration
// earlier: no exposed global latency. No global->VGPR loads in the loop.
// Fixed-M softmax (p = exp2(z*SC - 24)); P in [128][72] LDS, wave-private.
// id -> (half, xcd, head, qt) with qt reversed in upper half: paired blocks
// (id, id+256) share bh and sum to uniform 36 iters under round-robin.
// LDS 66KB -> 2 blocks/CU.
// ---------------------------------------------------------------------------
__global__ __launch_bounds__(256, 2)
void flash_attn(const bf16_t* __restrict__ Q, const bf16_t* __restrict__ Kg,
                const bf16_t* __restrict__ VT, bf16_t* __restrict__ O)
{
    constexpr int S = 2048, D = 2048;
    constexpr int PSTR = 72;
    __shared__ bf16_t Kb[2][64 * 128];   // [k_row][d], chunk-swizzled
    __shared__ bf16_t Vb[2][128 * 64];   // [d][k_row], chunk-swizzled
    __shared__ bf16_t Ps[128 * PSTR];

    const int tid  = threadIdx.x;
    const int w    = tid >> 6, lane = tid & 63, l16 = lane & 15, quad = lane >> 4;
    const int l7   = l16 & 7;

    const int id   = blockIdx.x;
    const int half = id >> 8;            // 0: qt 0..7, 1: qt 15..8
    const int rest = id & 255;
    const int xcd  = rest & 7;
    const int s    = rest >> 3;          // 0..31
    const int hh   = s & 3;
    const int qh   = s >> 2;             // 0..7
    const int qt   = half ? (15 - qh) : qh;
    const int bh   = xcd * 4 + hh;
    const int b    = bh >> 4, h = bh & 15;
    const int q0   = qt * 128;

    // Q fragments (B-operand): n = q (l16), k = d
    bf16x8 qf[2][4];
    {
        const bf16_t* qp = Q + (long)(b * S + q0 + w * 32 + l16) * D + h * 128 + quad * 8;
        #pragma unroll
        for (int qi = 0; qi < 2; ++qi)
            #pragma unroll
            for (int kk = 0; kk < 4; ++kk)
                qf[qi][kk] = *(const bf16x8*)(qp + qi * 16 * D + kk * 32);
    }

    // staging offsets (XOR chunk swizzle). K: 1024 chunks [64 rows][16 slots];
    // V^T: 1024 chunks [128 rows][8 slots].
    int koff[4], vof[4];
    #pragma unroll
    for (int i = 0; i < 4; ++i) {
        const int c  = i * 256 + tid;
        const int kr = c >> 4, cs = c & 15;
        const int cc = (cs & 8) | ((cs & 7) ^ (kr & 7));
        koff[i] = kr * D + cc * 8;
        const int d  = c >> 3, vs = c & 7;
        vof[i] = d * S + (vs ^ (d & 7)) * 8;
    }
    const bf16_t* Kst = Kg + (long)b * S * D + h * 128;
    const bf16_t* Vst = VT + (long)bh * 128 * S;

    f32x4 oacc[2][8] = {};
    float li[2] = { 0.f, 0.f };
    const float SC = 0.08838834764831845f * 1.44269504088896340f;

    const int nkt = 2 * qt + 2;

    // prologue: stage K[0], V[0] into buffer 0
    #pragma unroll
    for (int i = 0; i < 4; ++i) {
        async_copy16(Kst + koff[i], &Kb[0][i * 2048 + w * 512]);
        async_copy16(Vst + vof[i], &Vb[0][i * 2048 + w * 512]);
    }

    for (int kt = 0; kt < nkt; ++kt) {
        __syncthreads();   // drains prefetch issued 1 iter ago; guards bufs
        // ---- prefetch next tile (clamped refetch on last iter) ----
        const int nk = (kt + 1 < nkt) ? kt + 1 : kt;
        #pragma unroll
        for (int i = 0; i < 4; ++i) {
            async_copy16(Kst + (long)nk * 64 * D + koff[i],
                         &Kb[(kt + 1) & 1][i * 2048 + w * 512]);
            async_copy16(Vst + (long)nk * 64 + vof[i],
                         &Vb[(kt + 1) & 1][i * 2048 + w * 512]);
        }

        const bool active = (kt * 64 <= q0 + w * 32 + 31);
        if (active) {
            // ---- S^T = K·Q^T ----
            f32x4 sc[4][2] = {};
            const bf16_t* Kcur = Kb[kt & 1];
            #pragma unroll
            for (int kk = 0; kk < 4; ++kk)
                #pragma unroll
                for (int mt = 0; mt < 4; ++mt) {
                    const int cc = kk * 4 + quad;
                    const bf16x8 kf = *(const bf16x8*)
                        &Kcur[(mt * 16 + l16) * 128 + ((cc & 8) | ((cc & 7) ^ l7)) * 8];
                    sc[mt][0] = __builtin_amdgcn_mfma_f32_16x16x32_bf16(
                        kf, qf[0][kk], sc[mt][0], 0, 0, 0);
                    sc[mt][1] = __builtin_amdgcn_mfma_f32_16x16x32_bf16(
                        kf, qf[1][kk], sc[mt][1], 0, 0, 0);
                }

            // ---- fixed-M softmax + packed P writes ----
            #pragma unroll
            for (int qi = 0; qi < 2; ++qi) {
                const int qg = q0 + w * 32 + qi * 16 + l16;
                float rs = 0.f;
                #pragma unroll
                for (int mt = 0; mt < 4; ++mt) {
                    bf16x4 pk;
                    #pragma unroll
                    for (int r = 0; r < 4; ++r) {
                        const int kg = kt * 64 + mt * 16 + quad * 4 + r;
                        const float p = (kg > qg) ? 0.f
                                      : exp2f(sc[mt][qi][r] * SC - 24.0f);
                        rs += p;
                        pk[r] = (bf16_t)p;
                    }
                    *(bf16x4*)&Ps[(w * 32 + qi * 16 + l16) * PSTR + mt * 16 + quad * 4] = pk;
                }
                li[qi] += rs;
            }

            // ---- O += P·V^T (V from LDS, same parity as K) ----
            const bf16_t* Vcur = Vb[kt & 1];
            #pragma unroll
            for (int ks = 0; ks < 2; ++ks) {
                const bf16x8 pf0 = *(const bf16x8*)
                    &Ps[(w * 32 + l16) * PSTR + ks * 32 + quad * 8];
                const bf16x8 pf1 = *(const bf16x8*)
                    &Ps[(w * 32 + 16 + l16) * PSTR + ks * 32 + quad * 8];
                #pragma unroll
                for (int nv = 0; nv < 8; ++nv) {
                    const bf16x8 vf = *(const bf16x8*)
                        &Vcur[(nv * 16 + l16) * 64 + ((ks * 4 + quad) ^ l7) * 8];
                    oacc[0][nv] = __builtin_amdgcn_mfma_f32_16x16x32_bf16(
                        pf0, vf, oacc[0][nv], 0, 0, 0);
                    oacc[1][nv] = __builtin_amdgcn_mfma_f32_16x16x32_bf16(
                        pf1, vf, oacc[1][nv], 0, 0, 0);
                }
            }
        }
    }

    // ---- epilogue: reduce li across quads, normalize, store ----
    #pragma unroll
    for (int qi = 0; qi < 2; ++qi) {
        li[qi] += __shfl_xor(li[qi], 16);
        li[qi] += __shfl_xor(li[qi], 32);
        const float inv = 1.0f / li[qi];
        #pragma unroll
        for (int r = 0; r < 4; ++r) {
            const float invr = __shfl(inv, quad * 4 + r);
            const long  row  = (long)(b * S + q0 + w * 32 + qi * 16 + quad * 4 + r);
            #pragma unroll
            for (int nv = 0; nv < 8; ++nv)
                O[row * D + h * 128 + nv * 16 + l16] = (bf16_t)(oacc[qi][nv][r] * invr);
        }
    }
}

// ---------------------------------------------------------------------------
extern "C" void kernel_launch(void* const* d_in, const int* in_sizes, int n_in,
                              void* d_out, int out_size, void* d_ws, size_t ws_size,
                              hipStream_t stream) {
    const float* x  = (const float*)d_in[0];
    const float* wq = (const float*)d_in[1];
    const float* wk = (const float*)d_in[2];
    const float* wv = (const float*)d_in[3];
    const float* wo = (const float*)d_in[4];
    const float* fc = (const float*)d_in[5];
    const float* fs = (const float*)d_in[6];

    char* ws = (char*)d_ws;
    bf16_t* xb  = (bf16_t*)(ws + 0);
    bf16_t* W3  = (bf16_t*)(ws + (16l << 20));
    bf16_t* wob = (bf16_t*)(ws + (40l << 20));
    bf16_t* Qb  = (bf16_t*)(ws + (48l << 20));
    bf16_t* Kb  = (bf16_t*)(ws + (64l << 20));
    bf16_t* VTb = (bf16_t*)(ws + (80l << 20));
    bf16_t* Ob  = xb;   // x dead after QKV projection

    cast_all<<<24576, 256, 0, stream>>>(x, wq, wk, wv, wo, xb, W3, wob);

    gemm_qkv<<<1536, 256, 0, stream>>>(xb, W3, Qb, Kb, VTb, fc, fs);

    flash_attn<<<512, 256, 0, stream>>>(Qb, Kb, VTb, Ob);

    gemm_out<<<512, 256, 0, stream>>>(Ob, wob, (float*)d_out);
}